// Round 12
// baseline (260.088 us; speedup 1.0000x reference)
//
#include <hip/hip_runtime.h>

// Sparse conv, sorted-message pipeline v10 (round-10 structure, no xcvt,
// deeper-MLP gather).
//   Round-11 lesson: the pipeline must pay ONE random 128B msg pass; write-side
//   (round 10) costs less than read-side + listscat (round 11). Revert to
//   write-permuted gemm. New: gemm gathers f32 x directly (67MB, L3-resident;
//   deletes the 25us xcvt pass), gather runs 16 rows/wave (16 independent
//   loads in flight vs 8).
//   memset cnt (d_out scratch) ; wf (W->frag) ; rank (ONE atomic pass ->
//   rank + histogram) ; scan1/2/3 -> starts ; gemm (slot = starts[om]+rank,
//   nt msg stores) ; gather (in-lane contiguous segment sum).

typedef __attribute__((ext_vector_type(8))) short bf16x8;
typedef __attribute__((ext_vector_type(8))) unsigned short u16x8;
typedef __attribute__((ext_vector_type(4))) unsigned short u16x4;
typedef __attribute__((ext_vector_type(4))) float f32x4;
typedef __attribute__((ext_vector_type(2))) float f32x2;

constexpr int KOFF = 27;
constexpr int M = 65536;
constexpr int CIN = 64;
constexpr int COUT = 64;
constexpr int NVOX = 262144;
constexpr int NMSG = KOFF * M;                 // 1,769,472
constexpr int TM_BLOCK = 512;
constexpr int TILES_PER_K = M / TM_BLOCK;      // 128
constexpr int SUBTILES = TM_BLOCK / (4 * 16);  // 8

static __device__ __forceinline__ short f2bf(float f) {
  unsigned u = __builtin_bit_cast(unsigned, f);
  unsigned r = (u + 0x7FFFu + ((u >> 16) & 1u)) >> 16;
  return (short)r;
}
static __device__ __forceinline__ float bf2f(unsigned short h) {
  return __builtin_bit_cast(float, (unsigned)h << 16);
}

// ---------------- W -> MFMA-fragment layout ----------------

__global__ __launch_bounds__(256) void wf_kernel(const float* __restrict__ W,
                                                 unsigned short* __restrict__ Wf) {
  // Wf[k][(t*2+u)*64 + l][j] = W[k][u*32+(l>>4)*8+j][t*16+(l&15)]
  int k = blockIdx.x;  // 0..26
  const float* Wk = W + (size_t)k * (CIN * COUT);
  unsigned short* dst = Wf + (size_t)k * 4096;
#pragma unroll
  for (int i = 0; i < 16; ++i) {
    int e = threadIdx.x * 16 + i;
    int j = e & 7, l = (e >> 3) & 63, tu = e >> 9;
    int t = tu >> 1, u = tu & 1;
    dst[e] = (unsigned short)f2bf(Wk[(u * 32 + (l >> 4) * 8 + j) * COUT + t * 16 + (l & 15)]);
  }
}

// ---------------- single atomic pass: rank + histogram ----------------

__global__ __launch_bounds__(256) void rank_kernel(const int* __restrict__ out_map,
                                                   int* __restrict__ cnt,
                                                   int* __restrict__ rank) {
  int i = (blockIdx.x * 256 + threadIdx.x) * 8;  // grid = NMSG/2048 = 864
  int4 a = *(const int4*)(out_map + i);
  int4 b = *(const int4*)(out_map + i + 4);
  int4 ra, rb;
  ra.x = atomicAdd(&cnt[a.x], 1);
  ra.y = atomicAdd(&cnt[a.y], 1);
  ra.z = atomicAdd(&cnt[a.z], 1);
  ra.w = atomicAdd(&cnt[a.w], 1);
  rb.x = atomicAdd(&cnt[b.x], 1);
  rb.y = atomicAdd(&cnt[b.y], 1);
  rb.z = atomicAdd(&cnt[b.z], 1);
  rb.w = atomicAdd(&cnt[b.w], 1);
  *(int4*)(rank + i) = ra;
  *(int4*)(rank + i + 4) = rb;
}

// ---------------- scan ----------------

__global__ __launch_bounds__(256) void scan1_kernel(const int* __restrict__ cnt,
                                                    int* __restrict__ starts,
                                                    int* __restrict__ blockSums) {
  __shared__ int s[256];
  int t = threadIdx.x, i = blockIdx.x * 256 + t;  // grid = 1024
  int c = cnt[i];
  s[t] = c; __syncthreads();
  for (int off = 1; off < 256; off <<= 1) {
    int add = (t >= off) ? s[t - off] : 0;
    __syncthreads(); s[t] += add; __syncthreads();
  }
  starts[i] = s[t] - c;
  if (t == 255) blockSums[blockIdx.x] = s[t];
}

__global__ __launch_bounds__(256) void scan2_kernel(int* __restrict__ bs) {
  __shared__ int s[256];
  int t = threadIdx.x;
  int v0 = bs[t*4], v1 = bs[t*4+1], v2 = bs[t*4+2], v3 = bs[t*4+3];
  int sum = v0 + v1 + v2 + v3;
  s[t] = sum; __syncthreads();
  for (int off = 1; off < 256; off <<= 1) {
    int add = (t >= off) ? s[t - off] : 0;
    __syncthreads(); s[t] += add; __syncthreads();
  }
  int run = s[t] - sum;
  bs[t*4] = run; run += v0;
  bs[t*4+1] = run; run += v1;
  bs[t*4+2] = run; run += v2;
  bs[t*4+3] = run;
}

__global__ __launch_bounds__(256) void scan3_kernel(int* __restrict__ starts,
                                                    const int* __restrict__ blockBase) {
  int i = blockIdx.x * 256 + threadIdx.x;  // grid = 1024
  starts[i] += blockBase[blockIdx.x];
  if (i == 0) starts[NVOX] = NMSG;  // sentinel
}

// ---------------- phase A: pipelined GEMM (f32 gather) -> nt msg at sorted slots --------

__global__ __launch_bounds__(256) void gemm_msg_kernel(
    const float* __restrict__ x, const unsigned short* __restrict__ Wf,
    const int* __restrict__ in_map, const int* __restrict__ out_map,
    const int* __restrict__ rank, const int* __restrict__ starts,
    unsigned short* __restrict__ msg) {
  const int k = blockIdx.x / TILES_PER_K;
  const int mblock = (blockIdx.x % TILES_PER_K) * TM_BLOCK;
  const int wave = threadIdx.x >> 6;
  const int l = threadIdx.x & 63;
  const int lg = l >> 4;
  const int lr = l & 15;

  bf16x8 bfrag[4][2];
  const bf16x8* wf = (const bf16x8*)(Wf + (size_t)k * 4096);
#pragma unroll
  for (int t = 0; t < 4; ++t)
#pragma unroll
    for (int u = 0; u < 2; ++u)
      bfrag[t][u] = wf[(t * 2 + u) * 64 + l];

  const int mwave = mblock + wave * (TM_BLOCK / 4);
  const int rb = k * M + mwave;

  // f32 gather + inline RNE cvt (identical rounding to the old xcvt pass).
  auto loadA = [&](int s, bf16x8& A0, bf16x8& A1) {
    int id = in_map[rb + s * 16 + lr];
    const float* xr = x + (size_t)id * CIN + lg * 8;
    float4 x0 = *(const float4*)(xr);
    float4 x1 = *(const float4*)(xr + 4);
    float4 x2 = *(const float4*)(xr + 32);
    float4 x3 = *(const float4*)(xr + 36);
    A0[0]=f2bf(x0.x); A0[1]=f2bf(x0.y); A0[2]=f2bf(x0.z); A0[3]=f2bf(x0.w);
    A0[4]=f2bf(x1.x); A0[5]=f2bf(x1.y); A0[6]=f2bf(x1.z); A0[7]=f2bf(x1.w);
    A1[0]=f2bf(x2.x); A1[1]=f2bf(x2.y); A1[2]=f2bf(x2.z); A1[3]=f2bf(x2.w);
    A1[4]=f2bf(x3.x); A1[5]=f2bf(x3.y); A1[6]=f2bf(x3.z); A1[7]=f2bf(x3.w);
  };

  int om[4], rk[4];
#pragma unroll
  for (int r = 0; r < 4; ++r) {
    om[r] = out_map[rb + lg * 4 + r];
    rk[r] = rank[rb + lg * 4 + r];
  }

  bf16x8 c0, c1, n0, n1;
  loadA(0, c0, c1);
  loadA(1, n0, n1);

#pragma unroll 1
  for (int s = 0; s < SUBTILES; ++s) {
    bf16x8 p0, p1;
    const bool have = (s + 2 < SUBTILES);
    if (have) loadA(s + 2, p0, p1);

    int omN[4], rkN[4];
    if (s + 1 < SUBTILES) {
      const int rowb = rb + (s + 1) * 16 + lg * 4;
#pragma unroll
      for (int r = 0; r < 4; ++r) { omN[r] = out_map[rowb + r]; rkN[r] = rank[rowb + r]; }
    } else {
#pragma unroll
      for (int r = 0; r < 4; ++r) { omN[r] = 0; rkN[r] = 0; }
    }
    int st[4];
#pragma unroll
    for (int r = 0; r < 4; ++r) st[r] = starts[om[r]];

    f32x4 acc[4] = {{0.f,0.f,0.f,0.f},{0.f,0.f,0.f,0.f},{0.f,0.f,0.f,0.f},{0.f,0.f,0.f,0.f}};
#pragma unroll
    for (int t = 0; t < 4; ++t) {
      acc[t] = __builtin_amdgcn_mfma_f32_16x16x32_bf16(c0, bfrag[t][0], acc[t], 0, 0, 0);
      acc[t] = __builtin_amdgcn_mfma_f32_16x16x32_bf16(c1, bfrag[t][1], acc[t], 0, 0, 0);
    }

    // Row layout: position p = lr*4 + t holds channel t*16 + lr.
#pragma unroll
    for (int r = 0; r < 4; ++r) {
      const int sl = st[r] + rk[r];
      u16x4 h;
      h[0] = (unsigned short)f2bf(acc[0][r]);
      h[1] = (unsigned short)f2bf(acc[1][r]);
      h[2] = (unsigned short)f2bf(acc[2][r]);
      h[3] = (unsigned short)f2bf(acc[3][r]);
      __builtin_nontemporal_store(h, (u16x4*)(msg + (size_t)sl * 64 + lr * 4));
    }

    c0 = n0; c1 = n1;
    if (have) { n0 = p0; n1 = p1; }
#pragma unroll
    for (int r = 0; r < 4; ++r) { om[r] = omN[r]; rk[r] = rkN[r]; }
  }
}

// ---------------- phase B: in-lane contiguous segment sum, 16 rows/wave --------

__global__ __launch_bounds__(256) void gather_out_kernel(
    const unsigned short* __restrict__ msg, const int* __restrict__ starts,
    float* __restrict__ out) {
  const int wid = (blockIdx.x * 256 + threadIdx.x) >> 6;  // grid = NVOX/64 blocks
  const int p = threadIdx.x & 63;
  const int r = p >> 3;   // row-slot 0..7
  const int c = p & 7;    // 16B chunk within the 128B msg row
  const int oA = wid * 16 + r;      // batch A voxel
  const int oB = oA + 8;            // batch B voxel

  const int baseA = starts[oA];
  const int nA = starts[oA + 1] - baseA;
  const int baseB = starts[oB];
  const int nB = starts[oB + 1] - baseB;
  const unsigned short* srcA = msg + (size_t)baseA * 64 + c * 8;
  const unsigned short* srcB = msg + (size_t)baseB * 64 + c * 8;

  // 16 independent preloads (two 8-row batches) -> deeper MLP than 8.
  u16x8 vA[8], vB[8];
#pragma unroll
  for (int i = 0; i < 8; ++i) {
    int sa = (i < nA) ? i : 0;
    vA[i] = __builtin_nontemporal_load((const u16x8*)(srcA + (size_t)sa * 64));
  }
#pragma unroll
  for (int i = 0; i < 8; ++i) {
    int sb = (i < nB) ? i : 0;
    vB[i] = __builtin_nontemporal_load((const u16x8*)(srcB + (size_t)sb * 64));
  }

  float accA[8] = {}, accB[8] = {};
#pragma unroll
  for (int i = 0; i < 8; ++i) {
    float mA = (i < nA) ? 1.0f : 0.0f;
    float mB = (i < nB) ? 1.0f : 0.0f;
#pragma unroll
    for (int d = 0; d < 8; ++d) {
      accA[d] = fmaf(mA, bf2f((unsigned short)vA[i][d]), accA[d]);
      accB[d] = fmaf(mB, bf2f((unsigned short)vB[i][d]), accB[d]);
    }
  }
  // Rare tails (n > 8), per-lane.
  for (int i = 8; i < nA; ++i) {
    u16x8 t = __builtin_nontemporal_load((const u16x8*)(srcA + (size_t)i * 64));
#pragma unroll
    for (int d = 0; d < 8; ++d) accA[d] += bf2f((unsigned short)t[d]);
  }
  for (int i = 8; i < nB; ++i) {
    u16x8 t = __builtin_nontemporal_load((const u16x8*)(srcB + (size_t)i * 64));
#pragma unroll
    for (int d = 0; d < 8; ++d) accB[d] += bf2f((unsigned short)t[d]);
  }

  // position q = c*8 + d -> channel (d&3)*16 + 2c + (d>>2); all 64 lanes store.
  float* orA = out + (size_t)oA * 64 + 2 * c;
  float* orB = out + (size_t)oB * 64 + 2 * c;
  f32x2 a0 = {accA[0], accA[4]}; f32x2 a1 = {accA[1], accA[5]};
  f32x2 a2 = {accA[2], accA[6]}; f32x2 a3 = {accA[3], accA[7]};
  f32x2 b0 = {accB[0], accB[4]}; f32x2 b1 = {accB[1], accB[5]};
  f32x2 b2 = {accB[2], accB[6]}; f32x2 b3 = {accB[3], accB[7]};
  __builtin_nontemporal_store(a0, (f32x2*)(orA));
  __builtin_nontemporal_store(a1, (f32x2*)(orA + 16));
  __builtin_nontemporal_store(a2, (f32x2*)(orA + 32));
  __builtin_nontemporal_store(a3, (f32x2*)(orA + 48));
  __builtin_nontemporal_store(b0, (f32x2*)(orB));
  __builtin_nontemporal_store(b1, (f32x2*)(orB + 16));
  __builtin_nontemporal_store(b2, (f32x2*)(orB + 32));
  __builtin_nontemporal_store(b3, (f32x2*)(orB + 48));
}

// ---------------- fallback (atomic scatter) ----------------

__global__ __launch_bounds__(256) void spconv_atomic_kernel(
    const float* __restrict__ x, const float* __restrict__ W,
    const int* __restrict__ in_map, const int* __restrict__ out_map,
    float* __restrict__ out) {
  const int k = blockIdx.x / TILES_PER_K;
  const int mblock = (blockIdx.x % TILES_PER_K) * TM_BLOCK;
  const int wave = threadIdx.x >> 6;
  const int l = threadIdx.x & 63;
  const int lg = l >> 4;
  const int lr = l & 15;
  bf16x8 bfrag[4][2];
  const float* Wk = W + (size_t)k * (CIN * COUT);
#pragma unroll
  for (int t = 0; t < 4; ++t)
#pragma unroll
    for (int u = 0; u < 2; ++u)
#pragma unroll
      for (int j = 0; j < 8; ++j)
        bfrag[t][u][j] = f2bf(Wk[(u * 32 + lg * 8 + j) * COUT + t * 16 + lr]);
  const int mwave = mblock + wave * (TM_BLOCK / 4);
#pragma unroll 1
  for (int s = 0; s < SUBTILES; ++s) {
    const int mbase = mwave + s * 16;
    const int in_idx = in_map[k * M + mbase + lr];
    const float* xr = x + (size_t)in_idx * CIN + lg * 8;
    float4 x0 = *(const float4*)(xr);
    float4 x1 = *(const float4*)(xr + 4);
    float4 x2 = *(const float4*)(xr + 32);
    float4 x3 = *(const float4*)(xr + 36);
    bf16x8 a0, a1;
    a0[0]=f2bf(x0.x); a0[1]=f2bf(x0.y); a0[2]=f2bf(x0.z); a0[3]=f2bf(x0.w);
    a0[4]=f2bf(x1.x); a0[5]=f2bf(x1.y); a0[6]=f2bf(x1.z); a0[7]=f2bf(x1.w);
    a1[0]=f2bf(x2.x); a1[1]=f2bf(x2.y); a1[2]=f2bf(x2.z); a1[3]=f2bf(x2.w);
    a1[4]=f2bf(x3.x); a1[5]=f2bf(x3.y); a1[6]=f2bf(x3.z); a1[7]=f2bf(x3.w);
    f32x4 acc[4] = {{0.f,0.f,0.f,0.f},{0.f,0.f,0.f,0.f},{0.f,0.f,0.f,0.f},{0.f,0.f,0.f,0.f}};
#pragma unroll
    for (int t = 0; t < 4; ++t) {
      acc[t] = __builtin_amdgcn_mfma_f32_16x16x32_bf16(a0, bfrag[t][0], acc[t], 0, 0, 0);
      acc[t] = __builtin_amdgcn_mfma_f32_16x16x32_bf16(a1, bfrag[t][1], acc[t], 0, 0, 0);
    }
    const int obase = k * M + mbase + lg * 4;
    int oidx[4];
#pragma unroll
    for (int r = 0; r < 4; ++r) oidx[r] = out_map[obase + r];
#pragma unroll
    for (int t = 0; t < 4; ++t)
#pragma unroll
      for (int r = 0; r < 4; ++r)
        atomicAdd(out + (size_t)oidx[r] * COUT + t * 16 + lr, acc[t][r]);
  }
}

extern "C" void kernel_launch(void* const* d_in, const int* in_sizes, int n_in,
                              void* d_out, int out_size, void* d_ws, size_t ws_size,
                              hipStream_t stream) {
  const float* x = (const float*)d_in[0];
  const float* W = (const float*)d_in[1];
  const int* in_map = (const int*)d_in[2];
  const int* out_map = (const int*)d_in[3];
  float* out = (float*)d_out;
  char* ws = (char*)d_ws;

  const size_t msg_b    = (size_t)NMSG * 128;        // 226,492,416
  const size_t rank_b   = (size_t)NMSG * 4;          //   7,077,888
  const size_t wf_b     = (size_t)KOFF * 4096 * 2;   //     221,184
  const size_t starts_b = (size_t)(NVOX + 1) * 4;    //   1,048,580
  const size_t cnt_b    = (size_t)NVOX * 4;          //   1,048,576 (d_out scratch)
  auto pad = [](size_t b) { return (b + 255) & ~(size_t)255; };

  size_t need = pad(msg_b) + pad(rank_b) + pad(wf_b) + pad(starts_b);  // ~234.8 MB
  bool outScratchOk = ((size_t)out_size * 4 >= cnt_b + 1024 * 4 + 256);

  if (ws_size < need || !outScratchOk) {
    hipMemsetAsync(d_out, 0, (size_t)out_size * sizeof(float), stream);
    spconv_atomic_kernel<<<dim3(KOFF * TILES_PER_K), dim3(256), 0, stream>>>(
        x, W, in_map, out_map, out);
    return;
  }

  size_t off = 0;
  unsigned short* msg = (unsigned short*)(ws + off); off += pad(msg_b);
  int* rank = (int*)(ws + off); off += pad(rank_b);
  unsigned short* Wf = (unsigned short*)(ws + off); off += pad(wf_b);
  int* starts = (int*)(ws + off); off += pad(starts_b);

  int* cnt  = (int*)d_out;        // dead before gather writes out
  int* bsum = (int*)d_out + NVOX;

  hipMemsetAsync(cnt, 0, cnt_b, stream);

  wf_kernel<<<dim3(KOFF), dim3(256), 0, stream>>>(W, Wf);
  rank_kernel<<<dim3(NMSG / 2048), dim3(256), 0, stream>>>(out_map, cnt, rank);

  scan1_kernel<<<dim3(NVOX / 256), dim3(256), 0, stream>>>(cnt, starts, bsum);
  scan2_kernel<<<dim3(1), dim3(256), 0, stream>>>(bsum);
  scan3_kernel<<<dim3(NVOX / 256), dim3(256), 0, stream>>>(starts, bsum);

  gemm_msg_kernel<<<dim3(KOFF * TILES_PER_K), dim3(256), 0, stream>>>(
      x, Wf, in_map, out_map, rank, starts, msg);

  gather_out_kernel<<<dim3(NVOX / 64), dim3(256), 0, stream>>>(msg, starts, out);
}

// Round 13
// 244.599 us; speedup vs baseline: 1.0633x; 1.0633x over previous
//
#include <hip/hip_runtime.h>

// Sparse conv, sorted-message pipeline v11 (round-10 revert + perm-gemm +
// cached-msg L3-staging experiment).
//   Round-12 falsified: f32 direct gather (+124MB FETCH) and 16-row gather
//   (VGPR blowup) both regressed. This round:
//   memset cnt (d_out scratch) ; xw (xcvt x->bf16 + W->frag) ; rank (ONE
//   atomic pass -> rank + histogram) ; scan1/2/3 -> starts ; permcalc
//   (perm[i] = starts[om[i]] + rank[i], pure streaming, ~5us — replaces both
//   round-8's 35us atomic scatter and round-10's in-gemm starts lookups) ;
//   gemm (round-8 form, 87us measured: reads perm, CACHED msg stores) ;
//   gather (8-row in-lane, CACHED msg loads — L3-staging experiment).

typedef __attribute__((ext_vector_type(8))) short bf16x8;
typedef __attribute__((ext_vector_type(8))) unsigned short u16x8;
typedef __attribute__((ext_vector_type(4))) unsigned short u16x4;
typedef __attribute__((ext_vector_type(4))) float f32x4;
typedef __attribute__((ext_vector_type(2))) float f32x2;

constexpr int KOFF = 27;
constexpr int M = 65536;
constexpr int CIN = 64;
constexpr int COUT = 64;
constexpr int NVOX = 262144;
constexpr int NMSG = KOFF * M;                 // 1,769,472
constexpr int TM_BLOCK = 512;
constexpr int TILES_PER_K = M / TM_BLOCK;      // 128
constexpr int SUBTILES = TM_BLOCK / (4 * 16);  // 8
constexpr int XCVT_BLOCKS = NVOX * CIN / 8 / 256;  // 8192

static __device__ __forceinline__ short f2bf(float f) {
  unsigned u = __builtin_bit_cast(unsigned, f);
  unsigned r = (u + 0x7FFFu + ((u >> 16) & 1u)) >> 16;
  return (short)r;
}
static __device__ __forceinline__ float bf2f(unsigned short h) {
  return __builtin_bit_cast(float, (unsigned)h << 16);
}

// ---------------- xcvt + W-fragment ----------------

__global__ __launch_bounds__(256) void xw_kernel(
    const float* __restrict__ x, const float* __restrict__ W,
    unsigned short* __restrict__ xb, unsigned short* __restrict__ Wf,
    int xcvtBlocks) {
  const int b = blockIdx.x;
  if (b < xcvtBlocks) {
    int i = b * 256 + threadIdx.x;
    const float4* p = (const float4*)x + (size_t)i * 2;
    float4 a = p[0], q = p[1];
    u16x8 h;
    h[0] = (unsigned short)f2bf(a.x); h[1] = (unsigned short)f2bf(a.y);
    h[2] = (unsigned short)f2bf(a.z); h[3] = (unsigned short)f2bf(a.w);
    h[4] = (unsigned short)f2bf(q.x); h[5] = (unsigned short)f2bf(q.y);
    h[6] = (unsigned short)f2bf(q.z); h[7] = (unsigned short)f2bf(q.w);
    *(u16x8*)(xb + (size_t)i * 8) = h;
  } else {
    // W[k] -> fragment order: Wf[k][(t*2+u)*64 + l][j] = W[k][u*32+(l>>4)*8+j][t*16+(l&15)]
    int k = b - xcvtBlocks;  // 0..26
    const float* Wk = W + (size_t)k * (CIN * COUT);
    unsigned short* dst = Wf + (size_t)k * 4096;
#pragma unroll
    for (int i = 0; i < 16; ++i) {
      int e = threadIdx.x * 16 + i;
      int j = e & 7, l = (e >> 3) & 63, tu = e >> 9;
      int t = tu >> 1, u = tu & 1;
      dst[e] = (unsigned short)f2bf(Wk[(u * 32 + (l >> 4) * 8 + j) * COUT + t * 16 + (l & 15)]);
    }
  }
}

// ---------------- single atomic pass: rank + histogram ----------------

__global__ __launch_bounds__(256) void rank_kernel(const int* __restrict__ out_map,
                                                   int* __restrict__ cnt,
                                                   int* __restrict__ rank) {
  int i = (blockIdx.x * 256 + threadIdx.x) * 4;  // grid = NMSG/1024 = 1728
  int4 om = *(const int4*)(out_map + i);
  int4 rk;
  rk.x = atomicAdd(&cnt[om.x], 1);
  rk.y = atomicAdd(&cnt[om.y], 1);
  rk.z = atomicAdd(&cnt[om.z], 1);
  rk.w = atomicAdd(&cnt[om.w], 1);
  *(int4*)(rank + i) = rk;
}

// ---------------- scan ----------------

__global__ __launch_bounds__(256) void scan1_kernel(const int* __restrict__ cnt,
                                                    int* __restrict__ starts,
                                                    int* __restrict__ blockSums) {
  __shared__ int s[256];
  int t = threadIdx.x, i = blockIdx.x * 256 + t;  // grid = 1024
  int c = cnt[i];
  s[t] = c; __syncthreads();
  for (int off = 1; off < 256; off <<= 1) {
    int add = (t >= off) ? s[t - off] : 0;
    __syncthreads(); s[t] += add; __syncthreads();
  }
  starts[i] = s[t] - c;
  if (t == 255) blockSums[blockIdx.x] = s[t];
}

__global__ __launch_bounds__(256) void scan2_kernel(int* __restrict__ bs) {
  __shared__ int s[256];
  int t = threadIdx.x;
  int v0 = bs[t*4], v1 = bs[t*4+1], v2 = bs[t*4+2], v3 = bs[t*4+3];
  int sum = v0 + v1 + v2 + v3;
  s[t] = sum; __syncthreads();
  for (int off = 1; off < 256; off <<= 1) {
    int add = (t >= off) ? s[t - off] : 0;
    __syncthreads(); s[t] += add; __syncthreads();
  }
  int run = s[t] - sum;
  bs[t*4] = run; run += v0;
  bs[t*4+1] = run; run += v1;
  bs[t*4+2] = run; run += v2;
  bs[t*4+3] = run;
}

__global__ __launch_bounds__(256) void scan3_kernel(int* __restrict__ starts,
                                                    const int* __restrict__ blockBase) {
  int i = blockIdx.x * 256 + threadIdx.x;  // grid = 1024
  starts[i] += blockBase[blockIdx.x];
  if (i == 0) starts[NVOX] = NMSG;  // sentinel
}

// ---------------- permcalc: perm[i] = starts[om[i]] + rank[i] (streaming) ----

__global__ __launch_bounds__(256) void permcalc_kernel(
    const int* __restrict__ out_map, const int* __restrict__ rank,
    const int* __restrict__ starts, int* __restrict__ perm) {
  int i = (blockIdx.x * 256 + threadIdx.x) * 4;  // grid = NMSG/1024
  int4 om = *(const int4*)(out_map + i);
  int4 rk = *(const int4*)(rank + i);
  int4 p;
  p.x = starts[om.x] + rk.x;
  p.y = starts[om.y] + rk.y;
  p.z = starts[om.z] + rk.z;
  p.w = starts[om.w] + rk.w;
  *(int4*)(perm + i) = p;
}

// ---------------- phase A: pipelined GEMM -> CACHED msg at sorted slots --------

__global__ __launch_bounds__(256) void gemm_msg_kernel(
    const unsigned short* __restrict__ xb, const unsigned short* __restrict__ Wf,
    const int* __restrict__ in_map, const int* __restrict__ perm,
    unsigned short* __restrict__ msg) {
  const int k = blockIdx.x / TILES_PER_K;
  const int mblock = (blockIdx.x % TILES_PER_K) * TM_BLOCK;
  const int wave = threadIdx.x >> 6;
  const int l = threadIdx.x & 63;
  const int lg = l >> 4;
  const int lr = l & 15;

  bf16x8 bfrag[4][2];
  const bf16x8* wf = (const bf16x8*)(Wf + (size_t)k * 4096);
#pragma unroll
  for (int t = 0; t < 4; ++t)
#pragma unroll
    for (int u = 0; u < 2; ++u)
      bfrag[t][u] = wf[(t * 2 + u) * 64 + l];

  const int mwave = mblock + wave * (TM_BLOCK / 4);
  const int rb = k * M + mwave;

  auto loadA = [&](int s, bf16x8& A0, bf16x8& A1) {
    int id = in_map[rb + s * 16 + lr];
    const unsigned short* xr = xb + (size_t)id * CIN + lg * 8;
    A0 = *(const bf16x8*)(xr);
    A1 = *(const bf16x8*)(xr + 32);
  };

  bf16x8 c0, c1, n0, n1;
  loadA(0, c0, c1);
  loadA(1, n0, n1);

#pragma unroll 1
  for (int s = 0; s < SUBTILES; ++s) {
    bf16x8 p0, p1;
    const bool have = (s + 2 < SUBTILES);
    if (have) loadA(s + 2, p0, p1);

    f32x4 acc[4] = {{0.f,0.f,0.f,0.f},{0.f,0.f,0.f,0.f},{0.f,0.f,0.f,0.f},{0.f,0.f,0.f,0.f}};
#pragma unroll
    for (int t = 0; t < 4; ++t) {
      acc[t] = __builtin_amdgcn_mfma_f32_16x16x32_bf16(c0, bfrag[t][0], acc[t], 0, 0, 0);
      acc[t] = __builtin_amdgcn_mfma_f32_16x16x32_bf16(c1, bfrag[t][1], acc[t], 0, 0, 0);
    }

    // Row layout: position p = lr*4 + t holds channel t*16 + lr.
    // CACHED stores (L3-staging experiment: msg lines consumed by gather
    // before eviction never pay the DRAM write+read round-trip).
    const int* pr = perm + rb + s * 16 + lg * 4;
#pragma unroll
    for (int r = 0; r < 4; ++r) {
      const int sl = pr[r];
      u16x4 h;
      h[0] = (unsigned short)f2bf(acc[0][r]);
      h[1] = (unsigned short)f2bf(acc[1][r]);
      h[2] = (unsigned short)f2bf(acc[2][r]);
      h[3] = (unsigned short)f2bf(acc[3][r]);
      *(u16x4*)(msg + (size_t)sl * 64 + lr * 4) = h;
    }

    c0 = n0; c1 = n1;
    if (have) { n0 = p0; n1 = p1; }
  }
}

// ---------------- phase B: in-lane contiguous segment sum (8 rows/wave) --------

__global__ __launch_bounds__(256) void gather_out_kernel(
    const unsigned short* __restrict__ msg, const int* __restrict__ starts,
    float* __restrict__ out) {
  const int wid = (blockIdx.x * 256 + threadIdx.x) >> 6;  // grid = NVOX/32 blocks
  const int p = threadIdx.x & 63;
  const int r = p >> 3;   // which of this wave's 8 output rows
  const int c = p & 7;    // 16B chunk within the 128B msg row
  const int o = wid * 8 + r;

  const int base = starts[o];
  const int n = starts[o + 1] - base;
  const unsigned short* src = msg + (size_t)base * 64 + c * 8;

  // CACHED loads (hit L3 where gemm's stores are still resident).
  u16x8 v[8];
#pragma unroll
  for (int i = 0; i < 8; ++i) {
    int safe = (i < n) ? i : 0;
    v[i] = *(const u16x8*)(src + (size_t)safe * 64);
  }
  float acc[8] = {};
#pragma unroll
  for (int i = 0; i < 8; ++i) {
    float m = (i < n) ? 1.0f : 0.0f;
#pragma unroll
    for (int d = 0; d < 8; ++d)
      acc[d] = fmaf(m, bf2f((unsigned short)v[i][d]), acc[d]);
  }
  for (int i = 8; i < n; ++i) {
    u16x8 t = *(const u16x8*)(src + (size_t)i * 64);
#pragma unroll
    for (int d = 0; d < 8; ++d) acc[d] += bf2f((unsigned short)t[d]);
  }

  // position q = c*8 + d -> channel (d&3)*16 + 2c + (d>>2); all 64 lanes store.
  float* orow = out + (size_t)o * 64 + 2 * c;
  f32x2 s0 = {acc[0], acc[4]};
  f32x2 s1 = {acc[1], acc[5]};
  f32x2 s2 = {acc[2], acc[6]};
  f32x2 s3 = {acc[3], acc[7]};
  __builtin_nontemporal_store(s0, (f32x2*)(orow));
  __builtin_nontemporal_store(s1, (f32x2*)(orow + 16));
  __builtin_nontemporal_store(s2, (f32x2*)(orow + 32));
  __builtin_nontemporal_store(s3, (f32x2*)(orow + 48));
}

// ---------------- fallback (atomic scatter) ----------------

__global__ __launch_bounds__(256) void spconv_atomic_kernel(
    const float* __restrict__ x, const float* __restrict__ W,
    const int* __restrict__ in_map, const int* __restrict__ out_map,
    float* __restrict__ out) {
  const int k = blockIdx.x / TILES_PER_K;
  const int mblock = (blockIdx.x % TILES_PER_K) * TM_BLOCK;
  const int wave = threadIdx.x >> 6;
  const int l = threadIdx.x & 63;
  const int lg = l >> 4;
  const int lr = l & 15;
  bf16x8 bfrag[4][2];
  const float* Wk = W + (size_t)k * (CIN * COUT);
#pragma unroll
  for (int t = 0; t < 4; ++t)
#pragma unroll
    for (int u = 0; u < 2; ++u)
#pragma unroll
      for (int j = 0; j < 8; ++j)
        bfrag[t][u][j] = f2bf(Wk[(u * 32 + lg * 8 + j) * COUT + t * 16 + lr]);
  const int mwave = mblock + wave * (TM_BLOCK / 4);
#pragma unroll 1
  for (int s = 0; s < SUBTILES; ++s) {
    const int mbase = mwave + s * 16;
    const int in_idx = in_map[k * M + mbase + lr];
    const float* xr = x + (size_t)in_idx * CIN + lg * 8;
    float4 x0 = *(const float4*)(xr);
    float4 x1 = *(const float4*)(xr + 4);
    float4 x2 = *(const float4*)(xr + 32);
    float4 x3 = *(const float4*)(xr + 36);
    bf16x8 a0, a1;
    a0[0]=f2bf(x0.x); a0[1]=f2bf(x0.y); a0[2]=f2bf(x0.z); a0[3]=f2bf(x0.w);
    a0[4]=f2bf(x1.x); a0[5]=f2bf(x1.y); a0[6]=f2bf(x1.z); a0[7]=f2bf(x1.w);
    a1[0]=f2bf(x2.x); a1[1]=f2bf(x2.y); a1[2]=f2bf(x2.z); a1[3]=f2bf(x2.w);
    a1[4]=f2bf(x3.x); a1[5]=f2bf(x3.y); a1[6]=f2bf(x3.z); a1[7]=f2bf(x3.w);
    f32x4 acc[4] = {{0.f,0.f,0.f,0.f},{0.f,0.f,0.f,0.f},{0.f,0.f,0.f,0.f},{0.f,0.f,0.f,0.f}};
#pragma unroll
    for (int t = 0; t < 4; ++t) {
      acc[t] = __builtin_amdgcn_mfma_f32_16x16x32_bf16(a0, bfrag[t][0], acc[t], 0, 0, 0);
      acc[t] = __builtin_amdgcn_mfma_f32_16x16x32_bf16(a1, bfrag[t][1], acc[t], 0, 0, 0);
    }
    const int obase = k * M + mbase + lg * 4;
    int oidx[4];
#pragma unroll
    for (int r = 0; r < 4; ++r) oidx[r] = out_map[obase + r];
#pragma unroll
    for (int t = 0; t < 4; ++t)
#pragma unroll
      for (int r = 0; r < 4; ++r)
        atomicAdd(out + (size_t)oidx[r] * COUT + t * 16 + lr, acc[t][r]);
  }
}

extern "C" void kernel_launch(void* const* d_in, const int* in_sizes, int n_in,
                              void* d_out, int out_size, void* d_ws, size_t ws_size,
                              hipStream_t stream) {
  const float* x = (const float*)d_in[0];
  const float* W = (const float*)d_in[1];
  const int* in_map = (const int*)d_in[2];
  const int* out_map = (const int*)d_in[3];
  float* out = (float*)d_out;
  char* ws = (char*)d_ws;

  const size_t msg_b    = (size_t)NMSG * 128;        // 226,492,416
  const size_t xb_b     = (size_t)NVOX * CIN * 2;    //  33,554,432
  const size_t perm_b   = (size_t)NMSG * 4;          //   7,077,888
  const size_t wf_b     = (size_t)KOFF * 4096 * 2;   //     221,184
  const size_t starts_b = (size_t)(NVOX + 1) * 4;    //   1,048,580
  const size_t cnt_b    = (size_t)NVOX * 4;          // d_out scratch
  const size_t rank_b   = (size_t)NMSG * 4;          // d_out scratch
  auto pad = [](size_t b) { return (b + 255) & ~(size_t)255; };

  size_t need = pad(msg_b) + pad(xb_b) + pad(perm_b) + pad(wf_b) + pad(starts_b);
  // = 268,394,752 B (fits 256 MiB ws; verified fitting in rounds 8-10)
  bool outScratchOk =
      ((size_t)out_size * 4 >= pad(cnt_b) + pad(1024 * 4) + pad(rank_b));

  if (ws_size < need || !outScratchOk) {
    hipMemsetAsync(d_out, 0, (size_t)out_size * sizeof(float), stream);
    spconv_atomic_kernel<<<dim3(KOFF * TILES_PER_K), dim3(256), 0, stream>>>(
        x, W, in_map, out_map, out);
    return;
  }

  size_t off = 0;
  unsigned short* msg = (unsigned short*)(ws + off); off += pad(msg_b);
  unsigned short* xb  = (unsigned short*)(ws + off); off += pad(xb_b);
  int* perm = (int*)(ws + off); off += pad(perm_b);
  unsigned short* Wf = (unsigned short*)(ws + off); off += pad(wf_b);
  int* starts = (int*)(ws + off);

  char* outs = (char*)d_out;
  size_t ooff = 0;
  int* cnt  = (int*)(outs + ooff); ooff += pad(cnt_b);
  int* bsum = (int*)(outs + ooff); ooff += pad(1024 * 4);
  int* rank = (int*)(outs + ooff);

  hipMemsetAsync(cnt, 0, cnt_b, stream);

  xw_kernel<<<dim3(XCVT_BLOCKS + KOFF), dim3(256), 0, stream>>>(x, W, xb, Wf, XCVT_BLOCKS);
  rank_kernel<<<dim3(NMSG / 1024), dim3(256), 0, stream>>>(out_map, cnt, rank);

  scan1_kernel<<<dim3(NVOX / 256), dim3(256), 0, stream>>>(cnt, starts, bsum);
  scan2_kernel<<<dim3(1), dim3(256), 0, stream>>>(bsum);
  scan3_kernel<<<dim3(NVOX / 256), dim3(256), 0, stream>>>(starts, bsum);

  permcalc_kernel<<<dim3(NMSG / 1024), dim3(256), 0, stream>>>(out_map, rank, starts, perm);

  gemm_msg_kernel<<<dim3(KOFF * TILES_PER_K), dim3(256), 0, stream>>>(
      xb, Wf, in_map, perm, msg);

  gather_out_kernel<<<dim3(NVOX / 32), dim3(256), 0, stream>>>(msg, starts, out);
}

// Round 15
// 235.228 us; speedup vs baseline: 1.1057x; 1.0398x over previous
//
#include <hip/hip_runtime.h>

// Sparse conv, sorted-message pipeline v12b (r14 fixed: nontemporal_load needs
// clang ext_vector, not HIP_vector_type float4).
//   Measured components: perm-gemm w/ nt stores = 87us (r8,r13); gather w/ nt
//   loads = ~71us (r10) minus ~64MB clamped-preload waste (predicated loads);
//   cached-msg L3 staging REGRESSED (r13, +18us) -> nt everywhere for msg.
//   memset cnt (d_out scratch) ; xw (nt-read x -> bf16 xb + W->frag) ;
//   rank (ONE atomic pass -> rank + histogram; atomic cost ~ count, r9) ;
//   scan1/2/3 -> starts ; permcalc (streaming perm = starts[om]+rank) ;
//   gemm (dist-2 pipelined xb gather -> MFMA -> nt msg at perm[i]) ;
//   gather (8-row in-lane, PREDICATED nt loads, no mask-fma).

typedef __attribute__((ext_vector_type(8))) short bf16x8;
typedef __attribute__((ext_vector_type(8))) unsigned short u16x8;
typedef __attribute__((ext_vector_type(4))) unsigned short u16x4;
typedef __attribute__((ext_vector_type(4))) float f32x4;
typedef __attribute__((ext_vector_type(2))) float f32x2;

constexpr int KOFF = 27;
constexpr int M = 65536;
constexpr int CIN = 64;
constexpr int COUT = 64;
constexpr int NVOX = 262144;
constexpr int NMSG = KOFF * M;                 // 1,769,472
constexpr int TM_BLOCK = 512;
constexpr int TILES_PER_K = M / TM_BLOCK;      // 128
constexpr int SUBTILES = TM_BLOCK / (4 * 16);  // 8
constexpr int XCVT_BLOCKS = NVOX * CIN / 8 / 256;  // 8192

static __device__ __forceinline__ short f2bf(float f) {
  unsigned u = __builtin_bit_cast(unsigned, f);
  unsigned r = (u + 0x7FFFu + ((u >> 16) & 1u)) >> 16;
  return (short)r;
}
static __device__ __forceinline__ float bf2f(unsigned short h) {
  return __builtin_bit_cast(float, (unsigned)h << 16);
}

// ---------------- xcvt (nt x reads) + W-fragment ----------------

__global__ __launch_bounds__(256) void xw_kernel(
    const float* __restrict__ x, const float* __restrict__ W,
    unsigned short* __restrict__ xb, unsigned short* __restrict__ Wf,
    int xcvtBlocks) {
  const int b = blockIdx.x;
  if (b < xcvtBlocks) {
    int i = b * 256 + threadIdx.x;
    const f32x4* p = (const f32x4*)x + (size_t)i * 2;
    f32x4 a = __builtin_nontemporal_load(p);      // x read once: keep out of L3
    f32x4 q = __builtin_nontemporal_load(p + 1);
    u16x8 h;
    h[0] = (unsigned short)f2bf(a.x); h[1] = (unsigned short)f2bf(a.y);
    h[2] = (unsigned short)f2bf(a.z); h[3] = (unsigned short)f2bf(a.w);
    h[4] = (unsigned short)f2bf(q.x); h[5] = (unsigned short)f2bf(q.y);
    h[6] = (unsigned short)f2bf(q.z); h[7] = (unsigned short)f2bf(q.w);
    *(u16x8*)(xb + (size_t)i * 8) = h;            // cached: gemm re-reads xb
  } else {
    // W[k] -> fragment order: Wf[k][(t*2+u)*64 + l][j] = W[k][u*32+(l>>4)*8+j][t*16+(l&15)]
    int k = b - xcvtBlocks;  // 0..26
    const float* Wk = W + (size_t)k * (CIN * COUT);
    unsigned short* dst = Wf + (size_t)k * 4096;
#pragma unroll
    for (int i = 0; i < 16; ++i) {
      int e = threadIdx.x * 16 + i;
      int j = e & 7, l = (e >> 3) & 63, tu = e >> 9;
      int t = tu >> 1, u = tu & 1;
      dst[e] = (unsigned short)f2bf(Wk[(u * 32 + (l >> 4) * 8 + j) * COUT + t * 16 + (l & 15)]);
    }
  }
}

// ---------------- single atomic pass: rank + histogram ----------------

__global__ __launch_bounds__(256) void rank_kernel(const int* __restrict__ out_map,
                                                   int* __restrict__ cnt,
                                                   int* __restrict__ rank) {
  int i = (blockIdx.x * 256 + threadIdx.x) * 4;  // grid = NMSG/1024 = 1728
  int4 om = *(const int4*)(out_map + i);
  int4 rk;
  rk.x = atomicAdd(&cnt[om.x], 1);
  rk.y = atomicAdd(&cnt[om.y], 1);
  rk.z = atomicAdd(&cnt[om.z], 1);
  rk.w = atomicAdd(&cnt[om.w], 1);
  *(int4*)(rank + i) = rk;
}

// ---------------- scan ----------------

__global__ __launch_bounds__(256) void scan1_kernel(const int* __restrict__ cnt,
                                                    int* __restrict__ starts,
                                                    int* __restrict__ blockSums) {
  __shared__ int s[256];
  int t = threadIdx.x, i = blockIdx.x * 256 + t;  // grid = 1024
  int c = cnt[i];
  s[t] = c; __syncthreads();
  for (int off = 1; off < 256; off <<= 1) {
    int add = (t >= off) ? s[t - off] : 0;
    __syncthreads(); s[t] += add; __syncthreads();
  }
  starts[i] = s[t] - c;
  if (t == 255) blockSums[blockIdx.x] = s[t];
}

__global__ __launch_bounds__(256) void scan2_kernel(int* __restrict__ bs) {
  __shared__ int s[256];
  int t = threadIdx.x;
  int v0 = bs[t*4], v1 = bs[t*4+1], v2 = bs[t*4+2], v3 = bs[t*4+3];
  int sum = v0 + v1 + v2 + v3;
  s[t] = sum; __syncthreads();
  for (int off = 1; off < 256; off <<= 1) {
    int add = (t >= off) ? s[t - off] : 0;
    __syncthreads(); s[t] += add; __syncthreads();
  }
  int run = s[t] - sum;
  bs[t*4] = run; run += v0;
  bs[t*4+1] = run; run += v1;
  bs[t*4+2] = run; run += v2;
  bs[t*4+3] = run;
}

__global__ __launch_bounds__(256) void scan3_kernel(int* __restrict__ starts,
                                                    const int* __restrict__ blockBase) {
  int i = blockIdx.x * 256 + threadIdx.x;  // grid = 1024
  starts[i] += blockBase[blockIdx.x];
  if (i == 0) starts[NVOX] = NMSG;  // sentinel
}

// ---------------- permcalc: perm[i] = starts[om[i]] + rank[i] ----------------

__global__ __launch_bounds__(256) void permcalc_kernel(
    const int* __restrict__ out_map, const int* __restrict__ rank,
    const int* __restrict__ starts, int* __restrict__ perm) {
  int i = (blockIdx.x * 256 + threadIdx.x) * 4;  // grid = NMSG/1024
  int4 om = *(const int4*)(out_map + i);
  int4 rk = *(const int4*)(rank + i);
  int4 p;
  p.x = starts[om.x] + rk.x;
  p.y = starts[om.y] + rk.y;
  p.z = starts[om.z] + rk.z;
  p.w = starts[om.w] + rk.w;
  *(int4*)(perm + i) = p;
}

// ---------------- phase A: pipelined GEMM -> nt msg at sorted slots ----------------

__global__ __launch_bounds__(256) void gemm_msg_kernel(
    const unsigned short* __restrict__ xb, const unsigned short* __restrict__ Wf,
    const int* __restrict__ in_map, const int* __restrict__ perm,
    unsigned short* __restrict__ msg) {
  const int k = blockIdx.x / TILES_PER_K;
  const int mblock = (blockIdx.x % TILES_PER_K) * TM_BLOCK;
  const int wave = threadIdx.x >> 6;
  const int l = threadIdx.x & 63;
  const int lg = l >> 4;
  const int lr = l & 15;

  bf16x8 bfrag[4][2];
  const bf16x8* wf = (const bf16x8*)(Wf + (size_t)k * 4096);
#pragma unroll
  for (int t = 0; t < 4; ++t)
#pragma unroll
    for (int u = 0; u < 2; ++u)
      bfrag[t][u] = wf[(t * 2 + u) * 64 + l];

  const int mwave = mblock + wave * (TM_BLOCK / 4);
  const int rb = k * M + mwave;

  auto loadA = [&](int s, bf16x8& A0, bf16x8& A1) {
    int id = in_map[rb + s * 16 + lr];
    const unsigned short* xr = xb + (size_t)id * CIN + lg * 8;
    A0 = *(const bf16x8*)(xr);
    A1 = *(const bf16x8*)(xr + 32);
  };

  bf16x8 c0, c1, n0, n1;
  loadA(0, c0, c1);
  loadA(1, n0, n1);

#pragma unroll 1
  for (int s = 0; s < SUBTILES; ++s) {
    bf16x8 p0, p1;
    const bool have = (s + 2 < SUBTILES);
    if (have) loadA(s + 2, p0, p1);

    f32x4 acc[4] = {{0.f,0.f,0.f,0.f},{0.f,0.f,0.f,0.f},{0.f,0.f,0.f,0.f},{0.f,0.f,0.f,0.f}};
#pragma unroll
    for (int t = 0; t < 4; ++t) {
      acc[t] = __builtin_amdgcn_mfma_f32_16x16x32_bf16(c0, bfrag[t][0], acc[t], 0, 0, 0);
      acc[t] = __builtin_amdgcn_mfma_f32_16x16x32_bf16(c1, bfrag[t][1], acc[t], 0, 0, 0);
    }

    // Row layout: position p = lr*4 + t holds channel t*16 + lr.
    const int* pr = perm + rb + s * 16 + lg * 4;
#pragma unroll
    for (int r = 0; r < 4; ++r) {
      const int sl = pr[r];
      u16x4 h;
      h[0] = (unsigned short)f2bf(acc[0][r]);
      h[1] = (unsigned short)f2bf(acc[1][r]);
      h[2] = (unsigned short)f2bf(acc[2][r]);
      h[3] = (unsigned short)f2bf(acc[3][r]);
      __builtin_nontemporal_store(h, (u16x4*)(msg + (size_t)sl * 64 + lr * 4));
    }

    c0 = n0; c1 = n1;
    if (have) { n0 = p0; n1 = p1; }
  }
}

// ---------------- phase B: in-lane segment sum, predicated nt loads ----------

__global__ __launch_bounds__(256) void gather_out_kernel(
    const unsigned short* __restrict__ msg, const int* __restrict__ starts,
    float* __restrict__ out) {
  const int wid = (blockIdx.x * 256 + threadIdx.x) >> 6;  // grid = NVOX/32 blocks
  const int p = threadIdx.x & 63;
  const int r = p >> 3;   // which of this wave's 8 output rows
  const int c = p & 7;    // 16B chunk within the 128B msg row
  const int o = wid * 8 + r;

  const int base = starts[o];
  const int n = starts[o + 1] - base;
  const unsigned short* src = msg + (size_t)base * 64 + c * 8;

  // Predicated preloads: masked-off lanes issue NO memory traffic (vs the
  // old clamp-to-row-0 form, which under nt cost ~64MB of real DRAM reads).
  u16x8 v[8];
#pragma unroll
  for (int i = 0; i < 8; ++i) {
    v[i] = u16x8{0, 0, 0, 0, 0, 0, 0, 0};
    if (i < n)
      v[i] = __builtin_nontemporal_load((const u16x8*)(src + (size_t)i * 64));
  }
  float acc[8] = {};
#pragma unroll
  for (int i = 0; i < 8; ++i)
#pragma unroll
    for (int d = 0; d < 8; ++d)
      acc[d] += bf2f((unsigned short)v[i][d]);
  // Rare tail (n > 8), per-lane.
  for (int i = 8; i < n; ++i) {
    u16x8 t = __builtin_nontemporal_load((const u16x8*)(src + (size_t)i * 64));
#pragma unroll
    for (int d = 0; d < 8; ++d) acc[d] += bf2f((unsigned short)t[d]);
  }

  // position q = c*8 + d -> channel (d&3)*16 + 2c + (d>>2); all 64 lanes store.
  float* orow = out + (size_t)o * 64 + 2 * c;
  f32x2 s0 = {acc[0], acc[4]};
  f32x2 s1 = {acc[1], acc[5]};
  f32x2 s2 = {acc[2], acc[6]};
  f32x2 s3 = {acc[3], acc[7]};
  __builtin_nontemporal_store(s0, (f32x2*)(orow));
  __builtin_nontemporal_store(s1, (f32x2*)(orow + 16));
  __builtin_nontemporal_store(s2, (f32x2*)(orow + 32));
  __builtin_nontemporal_store(s3, (f32x2*)(orow + 48));
}

// ---------------- fallback (atomic scatter) ----------------

__global__ __launch_bounds__(256) void spconv_atomic_kernel(
    const float* __restrict__ x, const float* __restrict__ W,
    const int* __restrict__ in_map, const int* __restrict__ out_map,
    float* __restrict__ out) {
  const int k = blockIdx.x / TILES_PER_K;
  const int mblock = (blockIdx.x % TILES_PER_K) * TM_BLOCK;
  const int wave = threadIdx.x >> 6;
  const int l = threadIdx.x & 63;
  const int lg = l >> 4;
  const int lr = l & 15;
  bf16x8 bfrag[4][2];
  const float* Wk = W + (size_t)k * (CIN * COUT);
#pragma unroll
  for (int t = 0; t < 4; ++t)
#pragma unroll
    for (int u = 0; u < 2; ++u)
#pragma unroll
      for (int j = 0; j < 8; ++j)
        bfrag[t][u][j] = f2bf(Wk[(u * 32 + lg * 8 + j) * COUT + t * 16 + lr]);
  const int mwave = mblock + wave * (TM_BLOCK / 4);
#pragma unroll 1
  for (int s = 0; s < SUBTILES; ++s) {
    const int mbase = mwave + s * 16;
    const int in_idx = in_map[k * M + mbase + lr];
    const float* xr = x + (size_t)in_idx * CIN + lg * 8;
    float4 x0 = *(const float4*)(xr);
    float4 x1 = *(const float4*)(xr + 4);
    float4 x2 = *(const float4*)(xr + 32);
    float4 x3 = *(const float4*)(xr + 36);
    bf16x8 a0, a1;
    a0[0]=f2bf(x0.x); a0[1]=f2bf(x0.y); a0[2]=f2bf(x0.z); a0[3]=f2bf(x0.w);
    a0[4]=f2bf(x1.x); a0[5]=f2bf(x1.y); a0[6]=f2bf(x1.z); a0[7]=f2bf(x1.w);
    a1[0]=f2bf(x2.x); a1[1]=f2bf(x2.y); a1[2]=f2bf(x2.z); a1[3]=f2bf(x2.w);
    a1[4]=f2bf(x3.x); a1[5]=f2bf(x3.y); a1[6]=f2bf(x3.z); a1[7]=f2bf(x3.w);
    f32x4 acc[4] = {{0.f,0.f,0.f,0.f},{0.f,0.f,0.f,0.f},{0.f,0.f,0.f,0.f},{0.f,0.f,0.f,0.f}};
#pragma unroll
    for (int t = 0; t < 4; ++t) {
      acc[t] = __builtin_amdgcn_mfma_f32_16x16x32_bf16(a0, bfrag[t][0], acc[t], 0, 0, 0);
      acc[t] = __builtin_amdgcn_mfma_f32_16x16x32_bf16(a1, bfrag[t][1], acc[t], 0, 0, 0);
    }
    const int obase = k * M + mbase + lg * 4;
    int oidx[4];
#pragma unroll
    for (int r = 0; r < 4; ++r) oidx[r] = out_map[obase + r];
#pragma unroll
    for (int t = 0; t < 4; ++t)
#pragma unroll
      for (int r = 0; r < 4; ++r)
        atomicAdd(out + (size_t)oidx[r] * COUT + t * 16 + lr, acc[t][r]);
  }
}

extern "C" void kernel_launch(void* const* d_in, const int* in_sizes, int n_in,
                              void* d_out, int out_size, void* d_ws, size_t ws_size,
                              hipStream_t stream) {
  const float* x = (const float*)d_in[0];
  const float* W = (const float*)d_in[1];
  const int* in_map = (const int*)d_in[2];
  const int* out_map = (const int*)d_in[3];
  float* out = (float*)d_out;
  char* ws = (char*)d_ws;

  const size_t msg_b    = (size_t)NMSG * 128;        // 226,492,416
  const size_t xb_b     = (size_t)NVOX * CIN * 2;    //  33,554,432
  const size_t perm_b   = (size_t)NMSG * 4;          //   7,077,888
  const size_t wf_b     = (size_t)KOFF * 4096 * 2;   //     221,184
  const size_t starts_b = (size_t)(NVOX + 1) * 4;    //   1,048,580
  const size_t cnt_b    = (size_t)NVOX * 4;          // d_out scratch
  const size_t rank_b   = (size_t)NMSG * 4;          // d_out scratch
  auto pad = [](size_t b) { return (b + 255) & ~(size_t)255; };

  size_t need = pad(msg_b) + pad(xb_b) + pad(perm_b) + pad(wf_b) + pad(starts_b);
  bool outScratchOk =
      ((size_t)out_size * 4 >= pad(cnt_b) + pad(1024 * 4) + pad(rank_b));

  if (ws_size < need || !outScratchOk) {
    hipMemsetAsync(d_out, 0, (size_t)out_size * sizeof(float), stream);
    spconv_atomic_kernel<<<dim3(KOFF * TILES_PER_K), dim3(256), 0, stream>>>(
        x, W, in_map, out_map, out);
    return;
  }

  size_t off = 0;
  unsigned short* msg = (unsigned short*)(ws + off); off += pad(msg_b);
  unsigned short* xb  = (unsigned short*)(ws + off); off += pad(xb_b);
  int* perm = (int*)(ws + off); off += pad(perm_b);
  unsigned short* Wf = (unsigned short*)(ws + off); off += pad(wf_b);
  int* starts = (int*)(ws + off);

  char* outs = (char*)d_out;
  size_t ooff = 0;
  int* cnt  = (int*)(outs + ooff); ooff += pad(cnt_b);
  int* bsum = (int*)(outs + ooff); ooff += pad(1024 * 4);
  int* rank = (int*)(outs + ooff);

  hipMemsetAsync(cnt, 0, cnt_b, stream);

  xw_kernel<<<dim3(XCVT_BLOCKS + KOFF), dim3(256), 0, stream>>>(x, W, xb, Wf, XCVT_BLOCKS);
  rank_kernel<<<dim3(NMSG / 1024), dim3(256), 0, stream>>>(out_map, cnt, rank);

  scan1_kernel<<<dim3(NVOX / 256), dim3(256), 0, stream>>>(cnt, starts, bsum);
  scan2_kernel<<<dim3(1), dim3(256), 0, stream>>>(bsum);
  scan3_kernel<<<dim3(NVOX / 256), dim3(256), 0, stream>>>(starts, bsum);

  permcalc_kernel<<<dim3(NMSG / 1024), dim3(256), 0, stream>>>(out_map, rank, starts, perm);

  gemm_msg_kernel<<<dim3(KOFF * TILES_PER_K), dim3(256), 0, stream>>>(
      xb, Wf, in_map, perm, msg);

  gather_out_kernel<<<dim3(NVOX / 32), dim3(256), 0, stream>>>(msg, starts, out);
}

// Round 16
// 233.255 us; speedup vs baseline: 1.1150x; 1.0085x over previous
//
#include <hip/hip_runtime.h>

// Sparse conv, sorted-message pipeline v13 (best-measured assembly).
//   Component menu (measured across r8-r15):
//     gemm: perm-form + nt stores = 86us (best)  [r13/r15]
//     gather: clamped-nt 8-row = 71us (best)     [r10; predicated r15 ~80,
//             cached r13 ~89, 16-row r12 ~81 all worse]
//     front-end: xw(cached-x) 25 + rank 28 + scans 6 + permcalc 8
//   memset cnt (d_out scratch) ; xw ; rank (ONE atomic pass) ; scan1/2/3 ;
//   permcalc ; gemm (nt msg at perm[i]) ; gather (clamped-nt in-lane sum).

typedef __attribute__((ext_vector_type(8))) short bf16x8;
typedef __attribute__((ext_vector_type(8))) unsigned short u16x8;
typedef __attribute__((ext_vector_type(4))) unsigned short u16x4;
typedef __attribute__((ext_vector_type(4))) float f32x4;
typedef __attribute__((ext_vector_type(2))) float f32x2;

constexpr int KOFF = 27;
constexpr int M = 65536;
constexpr int CIN = 64;
constexpr int COUT = 64;
constexpr int NVOX = 262144;
constexpr int NMSG = KOFF * M;                 // 1,769,472
constexpr int TM_BLOCK = 512;
constexpr int TILES_PER_K = M / TM_BLOCK;      // 128
constexpr int SUBTILES = TM_BLOCK / (4 * 16);  // 8
constexpr int XCVT_BLOCKS = NVOX * CIN / 8 / 256;  // 8192

static __device__ __forceinline__ short f2bf(float f) {
  unsigned u = __builtin_bit_cast(unsigned, f);
  unsigned r = (u + 0x7FFFu + ((u >> 16) & 1u)) >> 16;
  return (short)r;
}
static __device__ __forceinline__ float bf2f(unsigned short h) {
  return __builtin_bit_cast(float, (unsigned)h << 16);
}

// ---------------- xcvt (cached x reads, r10 form) + W-fragment ----------------

__global__ __launch_bounds__(256) void xw_kernel(
    const float* __restrict__ x, const float* __restrict__ W,
    unsigned short* __restrict__ xb, unsigned short* __restrict__ Wf,
    int xcvtBlocks) {
  const int b = blockIdx.x;
  if (b < xcvtBlocks) {
    int i = b * 256 + threadIdx.x;
    const float4* p = (const float4*)x + (size_t)i * 2;
    float4 a = p[0], q = p[1];
    u16x8 h;
    h[0] = (unsigned short)f2bf(a.x); h[1] = (unsigned short)f2bf(a.y);
    h[2] = (unsigned short)f2bf(a.z); h[3] = (unsigned short)f2bf(a.w);
    h[4] = (unsigned short)f2bf(q.x); h[5] = (unsigned short)f2bf(q.y);
    h[6] = (unsigned short)f2bf(q.z); h[7] = (unsigned short)f2bf(q.w);
    *(u16x8*)(xb + (size_t)i * 8) = h;
  } else {
    // W[k] -> fragment order: Wf[k][(t*2+u)*64 + l][j] = W[k][u*32+(l>>4)*8+j][t*16+(l&15)]
    int k = b - xcvtBlocks;  // 0..26
    const float* Wk = W + (size_t)k * (CIN * COUT);
    unsigned short* dst = Wf + (size_t)k * 4096;
#pragma unroll
    for (int i = 0; i < 16; ++i) {
      int e = threadIdx.x * 16 + i;
      int j = e & 7, l = (e >> 3) & 63, tu = e >> 9;
      int t = tu >> 1, u = tu & 1;
      dst[e] = (unsigned short)f2bf(Wk[(u * 32 + (l >> 4) * 8 + j) * COUT + t * 16 + (l & 15)]);
    }
  }
}

// ---------------- single atomic pass: rank + histogram ----------------

__global__ __launch_bounds__(256) void rank_kernel(const int* __restrict__ out_map,
                                                   int* __restrict__ cnt,
                                                   int* __restrict__ rank) {
  int i = (blockIdx.x * 256 + threadIdx.x) * 4;  // grid = NMSG/1024 = 1728
  int4 om = *(const int4*)(out_map + i);
  int4 rk;
  rk.x = atomicAdd(&cnt[om.x], 1);
  rk.y = atomicAdd(&cnt[om.y], 1);
  rk.z = atomicAdd(&cnt[om.z], 1);
  rk.w = atomicAdd(&cnt[om.w], 1);
  *(int4*)(rank + i) = rk;
}

// ---------------- scan ----------------

__global__ __launch_bounds__(256) void scan1_kernel(const int* __restrict__ cnt,
                                                    int* __restrict__ starts,
                                                    int* __restrict__ blockSums) {
  __shared__ int s[256];
  int t = threadIdx.x, i = blockIdx.x * 256 + t;  // grid = 1024
  int c = cnt[i];
  s[t] = c; __syncthreads();
  for (int off = 1; off < 256; off <<= 1) {
    int add = (t >= off) ? s[t - off] : 0;
    __syncthreads(); s[t] += add; __syncthreads();
  }
  starts[i] = s[t] - c;
  if (t == 255) blockSums[blockIdx.x] = s[t];
}

__global__ __launch_bounds__(256) void scan2_kernel(int* __restrict__ bs) {
  __shared__ int s[256];
  int t = threadIdx.x;
  int v0 = bs[t*4], v1 = bs[t*4+1], v2 = bs[t*4+2], v3 = bs[t*4+3];
  int sum = v0 + v1 + v2 + v3;
  s[t] = sum; __syncthreads();
  for (int off = 1; off < 256; off <<= 1) {
    int add = (t >= off) ? s[t - off] : 0;
    __syncthreads(); s[t] += add; __syncthreads();
  }
  int run = s[t] - sum;
  bs[t*4] = run; run += v0;
  bs[t*4+1] = run; run += v1;
  bs[t*4+2] = run; run += v2;
  bs[t*4+3] = run;
}

__global__ __launch_bounds__(256) void scan3_kernel(int* __restrict__ starts,
                                                    const int* __restrict__ blockBase) {
  int i = blockIdx.x * 256 + threadIdx.x;  // grid = 1024
  starts[i] += blockBase[blockIdx.x];
  if (i == 0) starts[NVOX] = NMSG;  // sentinel
}

// ---------------- permcalc: perm[i] = starts[om[i]] + rank[i] ----------------

__global__ __launch_bounds__(256) void permcalc_kernel(
    const int* __restrict__ out_map, const int* __restrict__ rank,
    const int* __restrict__ starts, int* __restrict__ perm) {
  int i = (blockIdx.x * 256 + threadIdx.x) * 4;  // grid = NMSG/1024
  int4 om = *(const int4*)(out_map + i);
  int4 rk = *(const int4*)(rank + i);
  int4 p;
  p.x = starts[om.x] + rk.x;
  p.y = starts[om.y] + rk.y;
  p.z = starts[om.z] + rk.z;
  p.w = starts[om.w] + rk.w;
  *(int4*)(perm + i) = p;
}

// ---------------- phase A: pipelined GEMM -> nt msg at sorted slots ----------------

__global__ __launch_bounds__(256) void gemm_msg_kernel(
    const unsigned short* __restrict__ xb, const unsigned short* __restrict__ Wf,
    const int* __restrict__ in_map, const int* __restrict__ perm,
    unsigned short* __restrict__ msg) {
  const int k = blockIdx.x / TILES_PER_K;
  const int mblock = (blockIdx.x % TILES_PER_K) * TM_BLOCK;
  const int wave = threadIdx.x >> 6;
  const int l = threadIdx.x & 63;
  const int lg = l >> 4;
  const int lr = l & 15;

  bf16x8 bfrag[4][2];
  const bf16x8* wf = (const bf16x8*)(Wf + (size_t)k * 4096);
#pragma unroll
  for (int t = 0; t < 4; ++t)
#pragma unroll
    for (int u = 0; u < 2; ++u)
      bfrag[t][u] = wf[(t * 2 + u) * 64 + l];

  const int mwave = mblock + wave * (TM_BLOCK / 4);
  const int rb = k * M + mwave;

  auto loadA = [&](int s, bf16x8& A0, bf16x8& A1) {
    int id = in_map[rb + s * 16 + lr];
    const unsigned short* xr = xb + (size_t)id * CIN + lg * 8;
    A0 = *(const bf16x8*)(xr);
    A1 = *(const bf16x8*)(xr + 32);
  };

  bf16x8 c0, c1, n0, n1;
  loadA(0, c0, c1);
  loadA(1, n0, n1);

#pragma unroll 1
  for (int s = 0; s < SUBTILES; ++s) {
    bf16x8 p0, p1;
    const bool have = (s + 2 < SUBTILES);
    if (have) loadA(s + 2, p0, p1);

    f32x4 acc[4] = {{0.f,0.f,0.f,0.f},{0.f,0.f,0.f,0.f},{0.f,0.f,0.f,0.f},{0.f,0.f,0.f,0.f}};
#pragma unroll
    for (int t = 0; t < 4; ++t) {
      acc[t] = __builtin_amdgcn_mfma_f32_16x16x32_bf16(c0, bfrag[t][0], acc[t], 0, 0, 0);
      acc[t] = __builtin_amdgcn_mfma_f32_16x16x32_bf16(c1, bfrag[t][1], acc[t], 0, 0, 0);
    }

    // Row layout: position p = lr*4 + t holds channel t*16 + lr.
    const int* pr = perm + rb + s * 16 + lg * 4;
#pragma unroll
    for (int r = 0; r < 4; ++r) {
      const int sl = pr[r];
      u16x4 h;
      h[0] = (unsigned short)f2bf(acc[0][r]);
      h[1] = (unsigned short)f2bf(acc[1][r]);
      h[2] = (unsigned short)f2bf(acc[2][r]);
      h[3] = (unsigned short)f2bf(acc[3][r]);
      __builtin_nontemporal_store(h, (u16x4*)(msg + (size_t)sl * 64 + lr * 4));
    }

    c0 = n0; c1 = n1;
    if (have) { n0 = p0; n1 = p1; }
  }
}

// ---------------- phase B: in-lane segment sum (r10 exact: clamped nt loads) --

__global__ __launch_bounds__(256) void gather_out_kernel(
    const unsigned short* __restrict__ msg, const int* __restrict__ starts,
    float* __restrict__ out) {
  const int wid = (blockIdx.x * 256 + threadIdx.x) >> 6;  // grid = NVOX/32 blocks
  const int p = threadIdx.x & 63;
  const int r = p >> 3;   // which of this wave's 8 output rows
  const int c = p & 7;    // 16B chunk within the 128B msg row
  const int o = wid * 8 + r;

  const int base = starts[o];
  const int n = starts[o + 1] - base;
  const unsigned short* src = msg + (size_t)base * 64 + c * 8;

  // Clamped preloads (r10 form, measured 71us): duplicate row-0 loads are
  // L2-hits, and unconditional loads let all 8 issue back-to-back.
  u16x8 v[8];
#pragma unroll
  for (int i = 0; i < 8; ++i) {
    int safe = (i < n) ? i : 0;
    v[i] = __builtin_nontemporal_load((const u16x8*)(src + (size_t)safe * 64));
  }
  float acc[8] = {};
#pragma unroll
  for (int i = 0; i < 8; ++i) {
    float m = (i < n) ? 1.0f : 0.0f;
#pragma unroll
    for (int d = 0; d < 8; ++d)
      acc[d] = fmaf(m, bf2f((unsigned short)v[i][d]), acc[d]);
  }
  // Rare tail (n > 8), per-lane.
  for (int i = 8; i < n; ++i) {
    u16x8 t = __builtin_nontemporal_load((const u16x8*)(src + (size_t)i * 64));
#pragma unroll
    for (int d = 0; d < 8; ++d) acc[d] += bf2f((unsigned short)t[d]);
  }

  // position q = c*8 + d -> channel (d&3)*16 + 2c + (d>>2); all 64 lanes store.
  float* orow = out + (size_t)o * 64 + 2 * c;
  f32x2 s0 = {acc[0], acc[4]};
  f32x2 s1 = {acc[1], acc[5]};
  f32x2 s2 = {acc[2], acc[6]};
  f32x2 s3 = {acc[3], acc[7]};
  __builtin_nontemporal_store(s0, (f32x2*)(orow));
  __builtin_nontemporal_store(s1, (f32x2*)(orow + 16));
  __builtin_nontemporal_store(s2, (f32x2*)(orow + 32));
  __builtin_nontemporal_store(s3, (f32x2*)(orow + 48));
}

// ---------------- fallback (atomic scatter) ----------------

__global__ __launch_bounds__(256) void spconv_atomic_kernel(
    const float* __restrict__ x, const float* __restrict__ W,
    const int* __restrict__ in_map, const int* __restrict__ out_map,
    float* __restrict__ out) {
  const int k = blockIdx.x / TILES_PER_K;
  const int mblock = (blockIdx.x % TILES_PER_K) * TM_BLOCK;
  const int wave = threadIdx.x >> 6;
  const int l = threadIdx.x & 63;
  const int lg = l >> 4;
  const int lr = l & 15;
  bf16x8 bfrag[4][2];
  const float* Wk = W + (size_t)k * (CIN * COUT);
#pragma unroll
  for (int t = 0; t < 4; ++t)
#pragma unroll
    for (int u = 0; u < 2; ++u)
#pragma unroll
      for (int j = 0; j < 8; ++j)
        bfrag[t][u][j] = f2bf(Wk[(u * 32 + lg * 8 + j) * COUT + t * 16 + lr]);
  const int mwave = mblock + wave * (TM_BLOCK / 4);
#pragma unroll 1
  for (int s = 0; s < SUBTILES; ++s) {
    const int mbase = mwave + s * 16;
    const int in_idx = in_map[k * M + mbase + lr];
    const float* xr = x + (size_t)in_idx * CIN + lg * 8;
    float4 x0 = *(const float4*)(xr);
    float4 x1 = *(const float4*)(xr + 4);
    float4 x2 = *(const float4*)(xr + 32);
    float4 x3 = *(const float4*)(xr + 36);
    bf16x8 a0, a1;
    a0[0]=f2bf(x0.x); a0[1]=f2bf(x0.y); a0[2]=f2bf(x0.z); a0[3]=f2bf(x0.w);
    a0[4]=f2bf(x1.x); a0[5]=f2bf(x1.y); a0[6]=f2bf(x1.z); a0[7]=f2bf(x1.w);
    a1[0]=f2bf(x2.x); a1[1]=f2bf(x2.y); a1[2]=f2bf(x2.z); a1[3]=f2bf(x2.w);
    a1[4]=f2bf(x3.x); a1[5]=f2bf(x3.y); a1[6]=f2bf(x3.z); a1[7]=f2bf(x3.w);
    f32x4 acc[4] = {{0.f,0.f,0.f,0.f},{0.f,0.f,0.f,0.f},{0.f,0.f,0.f,0.f},{0.f,0.f,0.f,0.f}};
#pragma unroll
    for (int t = 0; t < 4; ++t) {
      acc[t] = __builtin_amdgcn_mfma_f32_16x16x32_bf16(a0, bfrag[t][0], acc[t], 0, 0, 0);
      acc[t] = __builtin_amdgcn_mfma_f32_16x16x32_bf16(a1, bfrag[t][1], acc[t], 0, 0, 0);
    }
    const int obase = k * M + mbase + lg * 4;
    int oidx[4];
#pragma unroll
    for (int r = 0; r < 4; ++r) oidx[r] = out_map[obase + r];
#pragma unroll
    for (int t = 0; t < 4; ++t)
#pragma unroll
      for (int r = 0; r < 4; ++r)
        atomicAdd(out + (size_t)oidx[r] * COUT + t * 16 + lr, acc[t][r]);
  }
}

extern "C" void kernel_launch(void* const* d_in, const int* in_sizes, int n_in,
                              void* d_out, int out_size, void* d_ws, size_t ws_size,
                              hipStream_t stream) {
  const float* x = (const float*)d_in[0];
  const float* W = (const float*)d_in[1];
  const int* in_map = (const int*)d_in[2];
  const int* out_map = (const int*)d_in[3];
  float* out = (float*)d_out;
  char* ws = (char*)d_ws;

  const size_t msg_b    = (size_t)NMSG * 128;        // 226,492,416
  const size_t xb_b     = (size_t)NVOX * CIN * 2;    //  33,554,432
  const size_t perm_b   = (size_t)NMSG * 4;          //   7,077,888
  const size_t wf_b     = (size_t)KOFF * 4096 * 2;   //     221,184
  const size_t starts_b = (size_t)(NVOX + 1) * 4;    //   1,048,580
  const size_t cnt_b    = (size_t)NVOX * 4;          // d_out scratch
  const size_t rank_b   = (size_t)NMSG * 4;          // d_out scratch
  auto pad = [](size_t b) { return (b + 255) & ~(size_t)255; };

  size_t need = pad(msg_b) + pad(xb_b) + pad(perm_b) + pad(wf_b) + pad(starts_b);
  bool outScratchOk =
      ((size_t)out_size * 4 >= pad(cnt_b) + pad(1024 * 4) + pad(rank_b));

  if (ws_size < need || !outScratchOk) {
    hipMemsetAsync(d_out, 0, (size_t)out_size * sizeof(float), stream);
    spconv_atomic_kernel<<<dim3(KOFF * TILES_PER_K), dim3(256), 0, stream>>>(
        x, W, in_map, out_map, out);
    return;
  }

  size_t off = 0;
  unsigned short* msg = (unsigned short*)(ws + off); off += pad(msg_b);
  unsigned short* xb  = (unsigned short*)(ws + off); off += pad(xb_b);
  int* perm = (int*)(ws + off); off += pad(perm_b);
  unsigned short* Wf = (unsigned short*)(ws + off); off += pad(wf_b);
  int* starts = (int*)(ws + off);

  char* outs = (char*)d_out;
  size_t ooff = 0;
  int* cnt  = (int*)(outs + ooff); ooff += pad(cnt_b);
  int* bsum = (int*)(outs + ooff); ooff += pad(1024 * 4);
  int* rank = (int*)(outs + ooff);

  hipMemsetAsync(cnt, 0, cnt_b, stream);

  xw_kernel<<<dim3(XCVT_BLOCKS + KOFF), dim3(256), 0, stream>>>(x, W, xb, Wf, XCVT_BLOCKS);
  rank_kernel<<<dim3(NMSG / 1024), dim3(256), 0, stream>>>(out_map, cnt, rank);

  scan1_kernel<<<dim3(NVOX / 256), dim3(256), 0, stream>>>(cnt, starts, bsum);
  scan2_kernel<<<dim3(1), dim3(256), 0, stream>>>(bsum);
  scan3_kernel<<<dim3(NVOX / 256), dim3(256), 0, stream>>>(starts, bsum);

  permcalc_kernel<<<dim3(NMSG / 1024), dim3(256), 0, stream>>>(out_map, rank, starts, perm);

  gemm_msg_kernel<<<dim3(KOFF * TILES_PER_K), dim3(256), 0, stream>>>(
      xb, Wf, in_map, perm, msg);

  gather_out_kernel<<<dim3(NVOX / 32), dim3(256), 0, stream>>>(msg, starts, out);
}

// Round 18
// 223.807 us; speedup vs baseline: 1.1621x; 1.0422x over previous
//
#include <hip/hip_runtime.h>

// Sparse conv, sorted-message pipeline — r10 configuration with HAZARD-FREE
// PLUMBING. r17 exposed a latent intermittent race (post-timing divergence
// 1.445): each graph replay began with an SDMA hipMemsetAsync on d_out's
// first 1MB (cnt scratch) racing the PREVIOUS replay's nontemporal gather
// stores to the same region. Fix: d_out is written by gather_out ONLY;
// cnt/starts merged into one ws buffer (in-place scan); zeroing done by a
// compute kernel folded into xw; no hipMemsetAsync in the main path.
//   xw: xcvt x->bf16 | W->MFMA-frag | zero starts          (~25us)
//   rank: ONE atomic pass rank[i]=atomicAdd(starts[om],1)  (~28us; starts
//     becomes the histogram; atomic cost = memory-side 32B RMW ~ count)
//   scan1/2/3: IN-PLACE exclusive prefix on starts + sentinel (~6us)
//   gemm: dist-2 pipelined xb gather -> bf16 MFMA -> nt msg row at
//     starts[om]+rank, om/rk prefetched one subtile ahead   (~96us)
//   gather: 8 rows/wave in-lane segment sum, clamped nt loads (~71us)

typedef __attribute__((ext_vector_type(8))) short bf16x8;
typedef __attribute__((ext_vector_type(8))) unsigned short u16x8;
typedef __attribute__((ext_vector_type(4))) unsigned short u16x4;
typedef __attribute__((ext_vector_type(4))) float f32x4;
typedef __attribute__((ext_vector_type(2))) float f32x2;

constexpr int KOFF = 27;
constexpr int M = 65536;
constexpr int CIN = 64;
constexpr int COUT = 64;
constexpr int NVOX = 262144;
constexpr int NMSG = KOFF * M;                 // 1,769,472
constexpr int TM_BLOCK = 512;
constexpr int TILES_PER_K = M / TM_BLOCK;      // 128
constexpr int SUBTILES = TM_BLOCK / (4 * 16);  // 8
constexpr int XCVT_BLOCKS = NVOX * CIN / 8 / 256;  // 8192
constexpr int ZERO_BLOCKS = NVOX / (256 * 4);      // 256 (int4 per thread)

static __device__ __forceinline__ short f2bf(float f) {
  unsigned u = __builtin_bit_cast(unsigned, f);
  unsigned r = (u + 0x7FFFu + ((u >> 16) & 1u)) >> 16;
  return (short)r;
}
static __device__ __forceinline__ float bf2f(unsigned short h) {
  return __builtin_bit_cast(float, (unsigned)h << 16);
}

// -------- xcvt + W-fragment + zero(starts) in one launch --------

__global__ __launch_bounds__(256) void xw_kernel(
    const float* __restrict__ x, const float* __restrict__ W,
    unsigned short* __restrict__ xb, unsigned short* __restrict__ Wf,
    int* __restrict__ starts, int xcvtBlocks) {
  const int b = blockIdx.x;
  if (b < xcvtBlocks) {
    int i = b * 256 + threadIdx.x;
    const float4* p = (const float4*)x + (size_t)i * 2;
    float4 a = p[0], q = p[1];
    u16x8 h;
    h[0] = (unsigned short)f2bf(a.x); h[1] = (unsigned short)f2bf(a.y);
    h[2] = (unsigned short)f2bf(a.z); h[3] = (unsigned short)f2bf(a.w);
    h[4] = (unsigned short)f2bf(q.x); h[5] = (unsigned short)f2bf(q.y);
    h[6] = (unsigned short)f2bf(q.z); h[7] = (unsigned short)f2bf(q.w);
    *(u16x8*)(xb + (size_t)i * 8) = h;
  } else if (b < xcvtBlocks + KOFF) {
    // W[k] -> fragment order: Wf[k][(t*2+u)*64 + l][j] = W[k][u*32+(l>>4)*8+j][t*16+(l&15)]
    int k = b - xcvtBlocks;  // 0..26
    const float* Wk = W + (size_t)k * (CIN * COUT);
    unsigned short* dst = Wf + (size_t)k * 4096;
#pragma unroll
    for (int i = 0; i < 16; ++i) {
      int e = threadIdx.x * 16 + i;
      int j = e & 7, l = (e >> 3) & 63, tu = e >> 9;
      int t = tu >> 1, u = tu & 1;
      dst[e] = (unsigned short)f2bf(Wk[(u * 32 + (l >> 4) * 8 + j) * COUT + t * 16 + (l & 15)]);
    }
  } else {
    // zero the starts/histogram buffer (compute path, no SDMA memset)
    int zb = b - xcvtBlocks - KOFF;                    // 0..ZERO_BLOCKS-1
    int i = (zb * 256 + threadIdx.x) * 4;              // covers NVOX ints
    *(int4*)(starts + i) = make_int4(0, 0, 0, 0);
  }
}

// -------- single atomic pass: rank + histogram (into starts) --------

__global__ __launch_bounds__(256) void rank_kernel(const int* __restrict__ out_map,
                                                   int* __restrict__ starts,
                                                   int* __restrict__ rank) {
  int i = (blockIdx.x * 256 + threadIdx.x) * 4;  // grid = NMSG/1024 = 1728
  int4 om = *(const int4*)(out_map + i);
  int4 rk;
  rk.x = atomicAdd(&starts[om.x], 1);
  rk.y = atomicAdd(&starts[om.y], 1);
  rk.z = atomicAdd(&starts[om.z], 1);
  rk.w = atomicAdd(&starts[om.w], 1);
  *(int4*)(rank + i) = rk;
}

// -------- in-place scan: starts (counts) -> exclusive prefix --------

__global__ __launch_bounds__(256) void scan1_kernel(int* __restrict__ starts,
                                                    int* __restrict__ blockSums) {
  __shared__ int s[256];
  int t = threadIdx.x, i = blockIdx.x * 256 + t;  // grid = 1024
  int c = starts[i];
  s[t] = c; __syncthreads();
  for (int off = 1; off < 256; off <<= 1) {
    int add = (t >= off) ? s[t - off] : 0;
    __syncthreads(); s[t] += add; __syncthreads();
  }
  starts[i] = s[t] - c;  // block-local exclusive (in place; 1 thread per elem)
  if (t == 255) blockSums[blockIdx.x] = s[t];
}

__global__ __launch_bounds__(256) void scan2_kernel(int* __restrict__ bs) {
  __shared__ int s[256];
  int t = threadIdx.x;
  int v0 = bs[t*4], v1 = bs[t*4+1], v2 = bs[t*4+2], v3 = bs[t*4+3];
  int sum = v0 + v1 + v2 + v3;
  s[t] = sum; __syncthreads();
  for (int off = 1; off < 256; off <<= 1) {
    int add = (t >= off) ? s[t - off] : 0;
    __syncthreads(); s[t] += add; __syncthreads();
  }
  int run = s[t] - sum;
  bs[t*4] = run; run += v0;
  bs[t*4+1] = run; run += v1;
  bs[t*4+2] = run; run += v2;
  bs[t*4+3] = run;
}

__global__ __launch_bounds__(256) void scan3_kernel(int* __restrict__ starts,
                                                    const int* __restrict__ blockBase) {
  int i = blockIdx.x * 256 + threadIdx.x;  // grid = 1024
  starts[i] += blockBase[blockIdx.x];
  if (i == 0) starts[NVOX] = NMSG;  // sentinel
}

// -------- phase A: pipelined GEMM -> nt msg at sorted slots --------

template <bool BF16IN>
__global__ __launch_bounds__(256) void gemm_msg_kernel(
    const void* __restrict__ xin, const unsigned short* __restrict__ Wf,
    const int* __restrict__ in_map, const int* __restrict__ out_map,
    const int* __restrict__ rank, const int* __restrict__ starts,
    unsigned short* __restrict__ msg) {
  const int k = blockIdx.x / TILES_PER_K;
  const int mblock = (blockIdx.x % TILES_PER_K) * TM_BLOCK;
  const int wave = threadIdx.x >> 6;
  const int l = threadIdx.x & 63;
  const int lg = l >> 4;
  const int lr = l & 15;

  bf16x8 bfrag[4][2];
  const bf16x8* wf = (const bf16x8*)(Wf + (size_t)k * 4096);
#pragma unroll
  for (int t = 0; t < 4; ++t)
#pragma unroll
    for (int u = 0; u < 2; ++u)
      bfrag[t][u] = wf[(t * 2 + u) * 64 + l];

  const int mwave = mblock + wave * (TM_BLOCK / 4);
  const int rb = k * M + mwave;

  auto loadA = [&](int s, bf16x8& A0, bf16x8& A1) {
    int id = in_map[rb + s * 16 + lr];
    if (BF16IN) {
      const unsigned short* xr = (const unsigned short*)xin + (size_t)id * CIN + lg * 8;
      A0 = *(const bf16x8*)(xr);
      A1 = *(const bf16x8*)(xr + 32);
    } else {
      const float* xr = (const float*)xin + (size_t)id * CIN + lg * 8;
      float4 x0 = *(const float4*)(xr);
      float4 x1 = *(const float4*)(xr + 4);
      float4 x2 = *(const float4*)(xr + 32);
      float4 x3 = *(const float4*)(xr + 36);
      A0[0]=f2bf(x0.x); A0[1]=f2bf(x0.y); A0[2]=f2bf(x0.z); A0[3]=f2bf(x0.w);
      A0[4]=f2bf(x1.x); A0[5]=f2bf(x1.y); A0[6]=f2bf(x1.z); A0[7]=f2bf(x1.w);
      A1[0]=f2bf(x2.x); A1[1]=f2bf(x2.y); A1[2]=f2bf(x2.z); A1[3]=f2bf(x2.w);
      A1[4]=f2bf(x3.x); A1[5]=f2bf(x3.y); A1[6]=f2bf(x3.z); A1[7]=f2bf(x3.w);
    }
  };

  int om[4], rk[4];
#pragma unroll
  for (int r = 0; r < 4; ++r) {
    om[r] = out_map[rb + lg * 4 + r];
    rk[r] = rank[rb + lg * 4 + r];
  }

  bf16x8 c0, c1, n0, n1;
  loadA(0, c0, c1);
  loadA(1, n0, n1);

#pragma unroll 1
  for (int s = 0; s < SUBTILES; ++s) {
    bf16x8 p0, p1;
    const bool have = (s + 2 < SUBTILES);
    if (have) loadA(s + 2, p0, p1);

    int omN[4], rkN[4];
    if (s + 1 < SUBTILES) {
      const int rowb = rb + (s + 1) * 16 + lg * 4;
#pragma unroll
      for (int r = 0; r < 4; ++r) { omN[r] = out_map[rowb + r]; rkN[r] = rank[rowb + r]; }
    } else {
#pragma unroll
      for (int r = 0; r < 4; ++r) { omN[r] = 0; rkN[r] = 0; }
    }
    int st[4];
#pragma unroll
    for (int r = 0; r < 4; ++r) st[r] = starts[om[r]];

    f32x4 acc[4] = {{0.f,0.f,0.f,0.f},{0.f,0.f,0.f,0.f},{0.f,0.f,0.f,0.f},{0.f,0.f,0.f,0.f}};
#pragma unroll
    for (int t = 0; t < 4; ++t) {
      acc[t] = __builtin_amdgcn_mfma_f32_16x16x32_bf16(c0, bfrag[t][0], acc[t], 0, 0, 0);
      acc[t] = __builtin_amdgcn_mfma_f32_16x16x32_bf16(c1, bfrag[t][1], acc[t], 0, 0, 0);
    }

    // Row layout: position p = lr*4 + t holds channel t*16 + lr.
#pragma unroll
    for (int r = 0; r < 4; ++r) {
      const int sl = st[r] + rk[r];
      u16x4 h;
      h[0] = (unsigned short)f2bf(acc[0][r]);
      h[1] = (unsigned short)f2bf(acc[1][r]);
      h[2] = (unsigned short)f2bf(acc[2][r]);
      h[3] = (unsigned short)f2bf(acc[3][r]);
      __builtin_nontemporal_store(h, (u16x4*)(msg + (size_t)sl * 64 + lr * 4));
    }

    c0 = n0; c1 = n1;
    if (have) { n0 = p0; n1 = p1; }
#pragma unroll
    for (int r = 0; r < 4; ++r) { om[r] = omN[r]; rk[r] = rkN[r]; }
  }
}

// -------- phase B: in-lane contiguous segment sum (sole writer of d_out) ----

__global__ __launch_bounds__(256) void gather_out_kernel(
    const unsigned short* __restrict__ msg, const int* __restrict__ starts,
    float* __restrict__ out) {
  const int wid = (blockIdx.x * 256 + threadIdx.x) >> 6;  // grid = NVOX/32 blocks
  const int p = threadIdx.x & 63;
  const int r = p >> 3;   // which of this wave's 8 output rows
  const int c = p & 7;    // 16B chunk within the 128B msg row
  const int o = wid * 8 + r;

  const int base = starts[o];
  const int n = starts[o + 1] - base;
  const unsigned short* src = msg + (size_t)base * 64 + c * 8;

  u16x8 v[8];
#pragma unroll
  for (int i = 0; i < 8; ++i) {
    int safe = (i < n) ? i : 0;
    v[i] = __builtin_nontemporal_load((const u16x8*)(src + (size_t)safe * 64));
  }
  float acc[8] = {};
#pragma unroll
  for (int i = 0; i < 8; ++i) {
    float m = (i < n) ? 1.0f : 0.0f;
#pragma unroll
    for (int d = 0; d < 8; ++d)
      acc[d] = fmaf(m, bf2f((unsigned short)v[i][d]), acc[d]);
  }
  for (int i = 8; i < n; ++i) {
    u16x8 t = __builtin_nontemporal_load((const u16x8*)(src + (size_t)i * 64));
#pragma unroll
    for (int d = 0; d < 8; ++d) acc[d] += bf2f((unsigned short)t[d]);
  }

  // position q = c*8 + d -> channel (d&3)*16 + 2c + (d>>2); all 64 lanes store.
  float* orow = out + (size_t)o * 64 + 2 * c;
  f32x2 s0 = {acc[0], acc[4]};
  f32x2 s1 = {acc[1], acc[5]};
  f32x2 s2 = {acc[2], acc[6]};
  f32x2 s3 = {acc[3], acc[7]};
  __builtin_nontemporal_store(s0, (f32x2*)(orow));
  __builtin_nontemporal_store(s1, (f32x2*)(orow + 16));
  __builtin_nontemporal_store(s2, (f32x2*)(orow + 32));
  __builtin_nontemporal_store(s3, (f32x2*)(orow + 48));
}

// -------- fallback (atomic scatter) --------

__global__ __launch_bounds__(256) void spconv_atomic_kernel(
    const float* __restrict__ x, const float* __restrict__ W,
    const int* __restrict__ in_map, const int* __restrict__ out_map,
    float* __restrict__ out) {
  const int k = blockIdx.x / TILES_PER_K;
  const int mblock = (blockIdx.x % TILES_PER_K) * TM_BLOCK;
  const int wave = threadIdx.x >> 6;
  const int l = threadIdx.x & 63;
  const int lg = l >> 4;
  const int lr = l & 15;
  bf16x8 bfrag[4][2];
  const float* Wk = W + (size_t)k * (CIN * COUT);
#pragma unroll
  for (int t = 0; t < 4; ++t)
#pragma unroll
    for (int u = 0; u < 2; ++u)
#pragma unroll
      for (int j = 0; j < 8; ++j)
        bfrag[t][u][j] = f2bf(Wk[(u * 32 + lg * 8 + j) * COUT + t * 16 + lr]);
  const int mwave = mblock + wave * (TM_BLOCK / 4);
#pragma unroll 1
  for (int s = 0; s < SUBTILES; ++s) {
    const int mbase = mwave + s * 16;
    const int in_idx = in_map[k * M + mbase + lr];
    const float* xr = x + (size_t)in_idx * CIN + lg * 8;
    float4 x0 = *(const float4*)(xr);
    float4 x1 = *(const float4*)(xr + 4);
    float4 x2 = *(const float4*)(xr + 32);
    float4 x3 = *(const float4*)(xr + 36);
    bf16x8 a0, a1;
    a0[0]=f2bf(x0.x); a0[1]=f2bf(x0.y); a0[2]=f2bf(x0.z); a0[3]=f2bf(x0.w);
    a0[4]=f2bf(x1.x); a0[5]=f2bf(x1.y); a0[6]=f2bf(x1.z); a0[7]=f2bf(x1.w);
    a1[0]=f2bf(x2.x); a1[1]=f2bf(x2.y); a1[2]=f2bf(x2.z); a1[3]=f2bf(x2.w);
    a1[4]=f2bf(x3.x); a1[5]=f2bf(x3.y); a1[6]=f2bf(x3.z); a1[7]=f2bf(x3.w);
    f32x4 acc[4] = {{0.f,0.f,0.f,0.f},{0.f,0.f,0.f,0.f},{0.f,0.f,0.f,0.f},{0.f,0.f,0.f,0.f}};
#pragma unroll
    for (int t = 0; t < 4; ++t) {
      acc[t] = __builtin_amdgcn_mfma_f32_16x16x32_bf16(a0, bfrag[t][0], acc[t], 0, 0, 0);
      acc[t] = __builtin_amdgcn_mfma_f32_16x16x32_bf16(a1, bfrag[t][1], acc[t], 0, 0, 0);
    }
    const int obase = k * M + mbase + lg * 4;
    int oidx[4];
#pragma unroll
    for (int r = 0; r < 4; ++r) oidx[r] = out_map[obase + r];
#pragma unroll
    for (int t = 0; t < 4; ++t)
#pragma unroll
      for (int r = 0; r < 4; ++r)
        atomicAdd(out + (size_t)oidx[r] * COUT + t * 16 + lr, acc[t][r]);
  }
}

extern "C" void kernel_launch(void* const* d_in, const int* in_sizes, int n_in,
                              void* d_out, int out_size, void* d_ws, size_t ws_size,
                              hipStream_t stream) {
  const float* x = (const float*)d_in[0];
  const float* W = (const float*)d_in[1];
  const int* in_map = (const int*)d_in[2];
  const int* out_map = (const int*)d_in[3];
  float* out = (float*)d_out;
  char* ws = (char*)d_ws;

  const size_t msg_b    = (size_t)NMSG * 128;        // 226,492,416
  const size_t xb_b     = (size_t)NVOX * CIN * 2;    //  33,554,432
  const size_t rank_b   = (size_t)NMSG * 4;          //   7,077,888
  const size_t wf_b     = (size_t)KOFF * 4096 * 2;   //     221,184
  const size_t starts_b = (size_t)(NVOX + 1) * 4;    //   1,048,580
  const size_t bsum_b   = 1024 * 4;
  auto pad = [](size_t b) { return (b + 255) & ~(size_t)255; };

  size_t need_p1 = pad(msg_b) + pad(rank_b) + pad(wf_b) + pad(starts_b) + pad(bsum_b);
  size_t need_p0 = need_p1 + pad(xb_b);  // 268,398,848 B <= 256 MiB ws
  bool useXb = (ws_size >= need_p0);

  if (ws_size < need_p1) {
    hipMemsetAsync(d_out, 0, (size_t)out_size * sizeof(float), stream);
    spconv_atomic_kernel<<<dim3(KOFF * TILES_PER_K), dim3(256), 0, stream>>>(
        x, W, in_map, out_map, out);
    return;
  }

  size_t off = 0;
  unsigned short* msg = (unsigned short*)(ws + off); off += pad(msg_b);
  unsigned short* xb = nullptr;
  if (useXb) { xb = (unsigned short*)(ws + off); off += pad(xb_b); }
  int* rank = (int*)(ws + off); off += pad(rank_b);
  unsigned short* Wf = (unsigned short*)(ws + off); off += pad(wf_b);
  int* starts = (int*)(ws + off); off += pad(starts_b);
  int* bsum = (int*)(ws + off);

  // xw zeroes starts (compute path); no SDMA memset, no d_out scratch.
  int xcvtBlocks = useXb ? XCVT_BLOCKS : 0;
  xw_kernel<<<dim3(xcvtBlocks + KOFF + ZERO_BLOCKS), dim3(256), 0, stream>>>(
      x, W, xb, Wf, starts, xcvtBlocks);

  rank_kernel<<<dim3(NMSG / 1024), dim3(256), 0, stream>>>(out_map, starts, rank);

  scan1_kernel<<<dim3(NVOX / 256), dim3(256), 0, stream>>>(starts, bsum);
  scan2_kernel<<<dim3(1), dim3(256), 0, stream>>>(bsum);
  scan3_kernel<<<dim3(NVOX / 256), dim3(256), 0, stream>>>(starts, bsum);

  if (useXb)
    gemm_msg_kernel<true><<<dim3(KOFF * TILES_PER_K), dim3(256), 0, stream>>>(
        (const void*)xb, Wf, in_map, out_map, rank, starts, msg);
  else
    gemm_msg_kernel<false><<<dim3(KOFF * TILES_PER_K), dim3(256), 0, stream>>>(
        (const void*)x, Wf, in_map, out_map, rank, starts, msg);

  gather_out_kernel<<<dim3(NVOX / 32), dim3(256), 0, stream>>>(msg, starts, out);
}